// Round 1
// baseline (277.815 us; speedup 1.0000x reference)
//
#include <hip/hip_runtime.h>
#include <hip/hip_bf16.h>

// ClusteringLayer: q[n,k] = norm_k( 1 / (1 + ||x_n - c_k||^2) ), alpha=1 (power = 1, no-op)
// N=131072, D=256, K=256, fp32 in/out. HBM-bound (~268MB floor ~43us).
// Strategy: fused bf16-MFMA GEMM for cross term; exact fp32 x_sq/c_sq; in-block
// row normalization (block covers all 256 clusters).

#define DDIM 256
#define KCL 256
#define BM 128          // rows per block (8 waves x 16 rows)
#define DCHUNK 64       // D-chunk staged in LDS for clusters

typedef __bf16 v8bf __attribute__((ext_vector_type(8)));
typedef float f32x4 __attribute__((ext_vector_type(4)));

__global__ __launch_bounds__(512, 4) void cluster_soft_assign(
    const float* __restrict__ X, const float* __restrict__ C,
    float* __restrict__ out)
{
    // B tile: [256 cols][64 d] bf16, XOR-swizzled (d' = d ^ ((col&7)<<3)) to kill
    // the stride-128B ds_read_b128 bank conflict (guide G4 / m214).
    __shared__ __align__(16) __bf16 Bs[KCL * DCHUNK];   // 32 KB
    __shared__ float csq_s[KCL];

    const int t    = threadIdx.x;
    const int wave = t >> 6;
    const int lane = t & 63;
    const int lr   = lane & 15;   // A-frag row / B-frag col / C col
    const int kg   = lane >> 4;   // k-group: k = kg*8 + j

    const long brow = (long)blockIdx.x * BM;
    const int  rowl = wave * 16 + lr;                 // A row this lane loads
    const float* xrow = X + (brow + rowl) * DDIM;

    // staging map: thread -> (cluster col, d-half of chunk)
    const int scol = t >> 1;
    const int sd0  = (t & 1) * 32;

    f32x4 acc[16];
#pragma unroll
    for (int i = 0; i < 16; ++i) { acc[i][0]=0.f; acc[i][1]=0.f; acc[i][2]=0.f; acc[i][3]=0.f; }

    float csq_part = 0.f;
    float xsq_part = 0.f;

    for (int c = 0; c < 4; ++c) {
        const int dbase = c * DCHUNK;

        // ---- A loads issued early (independent of LDS) to hide HBM latency
        const float4 a0 = *(const float4*)(xrow + dbase + kg * 8);
        const float4 a1 = *(const float4*)(xrow + dbase + kg * 8 + 4);
        const float4 a2 = *(const float4*)(xrow + dbase + 32 + kg * 8);
        const float4 a3 = *(const float4*)(xrow + dbase + 32 + kg * 8 + 4);

        if (c) __syncthreads();   // previous chunk's MFMA reads done before overwrite

        // ---- stage clusters chunk -> LDS (bf16, swizzled); accumulate c_sq in fp32
        const float* cp = C + (size_t)scol * DDIM + dbase + sd0;
#pragma unroll
        for (int g = 0; g < 4; ++g) {
            const float4 f0 = *(const float4*)(cp + g * 8);
            const float4 f1 = *(const float4*)(cp + g * 8 + 4);
            csq_part += f0.x*f0.x + f0.y*f0.y + f0.z*f0.z + f0.w*f0.w
                      + f1.x*f1.x + f1.y*f1.y + f1.z*f1.z + f1.w*f1.w;
            v8bf pk;
            pk[0]=(__bf16)f0.x; pk[1]=(__bf16)f0.y; pk[2]=(__bf16)f0.z; pk[3]=(__bf16)f0.w;
            pk[4]=(__bf16)f1.x; pk[5]=(__bf16)f1.y; pk[6]=(__bf16)f1.z; pk[7]=(__bf16)f1.w;
            const int dl = sd0 + g * 8;
            *(v8bf*)&Bs[scol * DCHUNK + (dl ^ ((scol & 7) << 3))] = pk;
        }
        __syncthreads();

        // ---- x_sq in exact fp32 (each X element touched by exactly one lane)
        xsq_part += a0.x*a0.x + a0.y*a0.y + a0.z*a0.z + a0.w*a0.w
                  + a1.x*a1.x + a1.y*a1.y + a1.z*a1.z + a1.w*a1.w
                  + a2.x*a2.x + a2.y*a2.y + a2.z*a2.z + a2.w*a2.w
                  + a3.x*a3.x + a3.y*a3.y + a3.z*a3.z + a3.w*a3.w;

        // ---- build A fragments (lane: row = lr, k = kg*8+j)
        v8bf af0, af1;
        af0[0]=(__bf16)a0.x; af0[1]=(__bf16)a0.y; af0[2]=(__bf16)a0.z; af0[3]=(__bf16)a0.w;
        af0[4]=(__bf16)a1.x; af0[5]=(__bf16)a1.y; af0[6]=(__bf16)a1.z; af0[7]=(__bf16)a1.w;
        af1[0]=(__bf16)a2.x; af1[1]=(__bf16)a2.y; af1[2]=(__bf16)a2.z; af1[3]=(__bf16)a2.w;
        af1[4]=(__bf16)a3.x; af1[5]=(__bf16)a3.y; af1[6]=(__bf16)a3.z; af1[7]=(__bf16)a3.w;

        const int dl0 = kg * 8;
        const int dl1 = 32 + kg * 8;
#pragma unroll
        for (int tl = 0; tl < 16; ++tl) {
            const int col = tl * 16 + lr;
            const v8bf bf0 = *(const v8bf*)&Bs[col * DCHUNK + (dl0 ^ ((col & 7) << 3))];
            acc[tl] = __builtin_amdgcn_mfma_f32_16x16x32_bf16(af0, bf0, acc[tl], 0, 0, 0);
        }
#pragma unroll
        for (int tl = 0; tl < 16; ++tl) {
            const int col = tl * 16 + lr;
            const v8bf bf1 = *(const v8bf*)&Bs[col * DCHUNK + (dl1 ^ ((col & 7) << 3))];
            acc[tl] = __builtin_amdgcn_mfma_f32_16x16x32_bf16(af1, bf1, acc[tl], 0, 0, 0);
        }
    }

    // ---- finish c_sq (pair t, t^1 staged complementary halves of the same col)
    csq_part += __shfl_xor(csq_part, 1);
    if ((t & 1) == 0) csq_s[scol] = csq_part;

    // ---- finish x_sq: reduce over the 4 k-groups; lane l then holds xsq(row l&15)
    float xsq = xsq_part;
    xsq += __shfl_xor(xsq, 16);
    xsq += __shfl_xor(xsq, 32);

    __syncthreads();   // csq_s visible

    // ---- epilogue: C/D layout col = lane&15, row = kg*4 + j (m89-verified)
#pragma unroll
    for (int j = 0; j < 4; ++j) {
        const long orow = brow + wave * 16 + kg * 4 + j;
        const float xs = __shfl(xsq, kg * 4 + j);   // xsq lives on lane (row index)
        float qv[16];
        float s = 0.f;
#pragma unroll
        for (int tl = 0; tl < 16; ++tl) {
            const float cs = csq_s[tl * 16 + lr];
            float d2 = xs + cs - 2.f * acc[tl][j];
            d2 = fmaxf(d2, 0.f);
            const float q = 1.f / (1.f + d2);
            qv[tl] = q;
            s += q;
        }
        // row-sum across the 16 lanes sharing kg (they hold this row's 256 cols)
        s += __shfl_xor(s, 1);
        s += __shfl_xor(s, 2);
        s += __shfl_xor(s, 4);
        s += __shfl_xor(s, 8);
        const float r = 1.f / s;
        float* op = out + orow * DDIM + lr;
#pragma unroll
        for (int tl = 0; tl < 16; ++tl) op[tl * 16] = qv[tl] * r;
    }
}

extern "C" void kernel_launch(void* const* d_in, const int* in_sizes, int n_in,
                              void* d_out, int out_size, void* d_ws, size_t ws_size,
                              hipStream_t stream) {
    const float* X = (const float*)d_in[0];   // (N, 256) fp32
    const float* C = (const float*)d_in[1];   // (256, 256) fp32
    float* out = (float*)d_out;               // (N, 256) fp32
    const int N = in_sizes[0] / DDIM;
    const int nblocks = N / BM;               // N = 131072 -> 1024 blocks
    hipLaunchKernelGGL(cluster_soft_assign, dim3(nblocks), dim3(512), 0, stream,
                       X, C, out);
}